// Round 1
// baseline (589.892 us; speedup 1.0000x reference)
//
#include <hip/hip_runtime.h>
#include <hip/hip_bf16.h>

#define EMBED 1024
#define SEQ   2048
#define NB    4
#define NH    16
#define HD    64
#define MROWS (NB*SEQ)   // 8192

typedef __attribute__((ext_vector_type(4))) float  f32x4;
typedef __attribute__((ext_vector_type(8))) short  s16x8;

#define MFMA16(a,b,c) __builtin_amdgcn_mfma_f32_16x16x32_bf16((a),(b),(c),0,0,0)

__device__ __forceinline__ unsigned short f2bf(float f) {
    union { float f; unsigned int u; } v; v.f = f;
    unsigned int r = v.u + 0x7fffu + ((v.u >> 16) & 1u);   // RTNE
    return (unsigned short)(r >> 16);
}
__device__ __forceinline__ unsigned int pack2(float a, float b) {
    return (unsigned int)f2bf(a) | ((unsigned int)f2bf(b) << 16);
}

// ---------------------------------------------------------------------------
// GEMM: Y[m,n] = sum_k A[m,k] * W[n,k] + bias[n]
//   AMODE 0: A fp32, convert to bf16 while staging. AMODE 1: A bf16.
//   OMODE 0: bf16 row-major [M][1024]
//   OMODE 1: bf16, V-transposed per head: Y[b][h][d][s]   (for PV operand)
//   OMODE 2: fp32 row-major (final output)
// Tile 128x128, BK=64, 256 threads (4 waves as 2x2 of 64x64).
// LDS row stride 72 shorts (144B): 16B-aligned b128 reads, <=2-way banks.
// ---------------------------------------------------------------------------
template<int AMODE, int OMODE>
__global__ __launch_bounds__(256) void gemm_xwT(
    const void* __restrict__ Ap, const float* __restrict__ W,
    const float* __restrict__ bias, void* __restrict__ Yp)
{
    __shared__ unsigned short Ald[128*72];
    __shared__ unsigned short Bld[128*72];
    const int t   = threadIdx.x;
    const int bm  = blockIdx.x, bn = blockIdx.y;
    const int wid = t >> 6, lane = t & 63, l15 = lane & 15, blk = lane >> 4;
    const int wr  = wid >> 1, wc = wid & 1;

    const float*          Af = (const float*)Ap;
    const unsigned short* Ab = (const unsigned short*)Ap;

    f32x4 acc[4][4] = {};

    for (int kt = 0; kt < EMBED/64; ++kt) {
        // ---- stage A tile [128][64] ----
        if (AMODE == 0) {
            #pragma unroll
            for (int i = 0; i < 8; ++i) {
                int f = t + 256*i, row = f >> 4, c4 = f & 15;
                float4 v = *(const float4*)(Af + (size_t)(bm*128+row)*EMBED + kt*64 + c4*4);
                *(uint2*)&Ald[row*72 + c4*4] = make_uint2(pack2(v.x,v.y), pack2(v.z,v.w));
            }
        } else {
            #pragma unroll
            for (int i = 0; i < 4; ++i) {
                int f = t + 256*i, row = f >> 3, c8 = f & 7;
                *(s16x8*)&Ald[row*72 + c8*8] =
                    *(const s16x8*)(Ab + (size_t)(bm*128+row)*EMBED + kt*64 + c8*8);
            }
        }
        // ---- stage B tile (W rows = output cols), fp32 -> bf16 ----
        #pragma unroll
        for (int i = 0; i < 8; ++i) {
            int f = t + 256*i, row = f >> 4, c4 = f & 15;
            float4 v = *(const float4*)(W + (size_t)(bn*128+row)*EMBED + kt*64 + c4*4);
            *(uint2*)&Bld[row*72 + c4*4] = make_uint2(pack2(v.x,v.y), pack2(v.z,v.w));
        }
        __syncthreads();
        // ---- compute ----
        #pragma unroll
        for (int ks = 0; ks < 2; ++ks) {
            s16x8 af[4], bf[4];
            #pragma unroll
            for (int mt = 0; mt < 4; ++mt)
                af[mt] = *(const s16x8*)&Ald[(wr*64 + mt*16 + l15)*72 + ks*32 + blk*8];
            #pragma unroll
            for (int nt = 0; nt < 4; ++nt)
                bf[nt] = *(const s16x8*)&Bld[(wc*64 + nt*16 + l15)*72 + ks*32 + blk*8];
            #pragma unroll
            for (int mt = 0; mt < 4; ++mt)
                #pragma unroll
                for (int nt = 0; nt < 4; ++nt)
                    acc[mt][nt] = MFMA16(af[mt], bf[nt], acc[mt][nt]);
        }
        __syncthreads();
    }

    // ---- epilogue ----
    float bv[4];
    #pragma unroll
    for (int nt = 0; nt < 4; ++nt)
        bv[nt] = bias[bn*128 + wc*64 + nt*16 + l15];

    unsigned short* Yb = (unsigned short*)Yp;
    float*          Yf = (float*)Yp;

    #pragma unroll
    for (int mt = 0; mt < 4; ++mt) {
        #pragma unroll
        for (int nt = 0; nt < 4; ++nt) {
            const int m0 = bm*128 + wr*64 + mt*16 + blk*4;     // rows m0..m0+3
            const int n  = bn*128 + wc*64 + nt*16 + l15;
            f32x4 a = acc[mt][nt];
            if (OMODE == 2) {
                #pragma unroll
                for (int r = 0; r < 4; ++r)
                    Yf[(size_t)(m0+r)*EMBED + n] = a[r] + bv[nt];
            } else if (OMODE == 0) {
                #pragma unroll
                for (int r = 0; r < 4; ++r)
                    Yb[(size_t)(m0+r)*EMBED + n] = f2bf(a[r] + bv[nt]);
            } else {
                // Vt[b][h][d][s], consecutive r = consecutive s -> ushort4
                const int b = m0 >> 11, s = m0 & (SEQ-1);
                const int h = n >> 6,  d = n & (HD-1);
                ushort4 pk;
                pk.x = f2bf(a[0] + bv[nt]); pk.y = f2bf(a[1] + bv[nt]);
                pk.z = f2bf(a[2] + bv[nt]); pk.w = f2bf(a[3] + bv[nt]);
                *(ushort4*)&Yb[(((size_t)b*NH + h)*HD + d)*SEQ + s] = pk;
            }
        }
    }
}

// ---------------------------------------------------------------------------
// Flash attention, per (b,h): 4 waves x 16 q-rows per block, k-step 32.
// Swapped QK^T: mfma(K,Q) -> lane holds q = lane&15, k = 16t + blk*4 + reg.
// Online softmax in exp2 domain; P repacked via per-wave LDS roundtrip into
// the PV A-fragment; V read from per-head transposed Vt[b][h][d][s].
// ---------------------------------------------------------------------------
__global__ __launch_bounds__(256) void attn_fwd(
    const unsigned short* __restrict__ Qp,
    const unsigned short* __restrict__ Kp,
    const unsigned short* __restrict__ Vt,
    unsigned short* __restrict__ ctx)
{
    __shared__ unsigned short Plds[4][16*40];   // per-wave 16 rows x 40 shorts (80B stride)
    const int t = threadIdx.x, wid = t >> 6, lane = t & 63;
    const int l15 = lane & 15, blk = lane >> 4;
    const int qb = blockIdx.x, bh = blockIdx.y;
    const int b = bh >> 4, h = bh & (NH-1);
    const int q0 = qb*64 + wid*16;

    // Q fragments (held whole kernel): B-operand, col=q=l15, k=d
    const unsigned short* qptr = Qp + (size_t)(b*SEQ + q0 + l15)*EMBED + h*HD;
    const s16x8 qf0 = *(const s16x8*)(qptr + blk*8);
    const s16x8 qf1 = *(const s16x8*)(qptr + 32 + blk*8);

    const unsigned short* kb = Kp + (size_t)b*SEQ*EMBED + h*HD;
    const unsigned short* vb = Vt + (size_t)bh*HD*SEQ;
    unsigned short* pl = &Plds[wid][0];

    f32x4 o[4] = {};
    float lsum = 0.f, m2 = -1e30f;
    const float sc2 = 0.125f * 1.44269504088896f;   // 1/sqrt(64) * log2(e)

    for (int k0 = 0; k0 < SEQ; k0 += 32) {
        // K fragments: A-operand, row = key = l15 (+16), k = d
        const unsigned short* kr0 = kb + (size_t)(k0 + l15)*EMBED;
        const unsigned short* kr1 = kr0 + (size_t)16*EMBED;
        s16x8 ka0 = *(const s16x8*)(kr0 + blk*8);
        s16x8 ka1 = *(const s16x8*)(kr0 + 32 + blk*8);
        s16x8 kc0 = *(const s16x8*)(kr1 + blk*8);
        s16x8 kc1 = *(const s16x8*)(kr1 + 32 + blk*8);

        f32x4 s0 = {}, s1 = {};
        s0 = MFMA16(ka0, qf0, s0);
        s0 = MFMA16(ka1, qf1, s0);
        s1 = MFMA16(kc0, qf0, s1);
        s1 = MFMA16(kc1, qf1, s1);
        // lane: q = l15; s0 regs -> k = k0 + blk*4 + r; s1 -> +16

        float pm = fmaxf(fmaxf(fmaxf(s0[0],s0[1]),fmaxf(s0[2],s0[3])),
                         fmaxf(fmaxf(s1[0],s1[1]),fmaxf(s1[2],s1[3])));
        pm = fmaxf(pm, __shfl_xor(pm, 16));
        pm = fmaxf(pm, __shfl_xor(pm, 32));
        const float m2n   = fmaxf(m2, pm * sc2);
        const float alpha = exp2f(m2 - m2n);
        const float p0 = exp2f(s0[0]*sc2 - m2n), p1 = exp2f(s0[1]*sc2 - m2n);
        const float p2 = exp2f(s0[2]*sc2 - m2n), p3 = exp2f(s0[3]*sc2 - m2n);
        const float p4 = exp2f(s1[0]*sc2 - m2n), p5 = exp2f(s1[1]*sc2 - m2n);
        const float p6 = exp2f(s1[2]*sc2 - m2n), p7 = exp2f(s1[3]*sc2 - m2n);
        float ps = ((p0+p1)+(p2+p3)) + ((p4+p5)+(p6+p7));
        ps += __shfl_xor(ps, 16);
        ps += __shfl_xor(ps, 32);
        lsum = lsum * alpha + ps;
        m2 = m2n;

        // rescale O (rows q_local = blk*4 + r; alpha lives at lane q)
        float ar[4];
        #pragma unroll
        for (int r = 0; r < 4; ++r) ar[r] = __shfl(alpha, blk*4 + r);
        #pragma unroll
        for (int dt = 0; dt < 4; ++dt)
            #pragma unroll
            for (int r = 0; r < 4; ++r) o[dt][r] *= ar[r];

        // P -> LDS (bf16, row q, cols k_local), read back PV A-fragment
        *(uint2*)&pl[l15*40 + blk*4]      = make_uint2(pack2(p0,p1), pack2(p2,p3));
        *(uint2*)&pl[l15*40 + 16 + blk*4] = make_uint2(pack2(p4,p5), pack2(p6,p7));
        s16x8 pf = *(const s16x8*)&pl[l15*40 + blk*8];

        // PV: B-operand from Vt rows (col = d = dt*16+l15, k = seq)
        const unsigned short* vr = vb + (size_t)l15*SEQ + k0 + blk*8;
        #pragma unroll
        for (int dt = 0; dt < 4; ++dt)
            o[dt] = MFMA16(pf, *(const s16x8*)(vr + (size_t)dt*16*SEQ), o[dt]);
    }

    float li[4];
    #pragma unroll
    for (int r = 0; r < 4; ++r) li[r] = 1.f / __shfl(lsum, blk*4 + r);

    unsigned short* cp = ctx + (size_t)(b*SEQ + q0)*EMBED + h*HD;
    #pragma unroll
    for (int dt = 0; dt < 4; ++dt)
        #pragma unroll
        for (int r = 0; r < 4; ++r)
            cp[(size_t)(blk*4 + r)*EMBED + dt*16 + l15] = f2bf(o[dt][r] * li[r]);
}

// ---------------------------------------------------------------------------
extern "C" void kernel_launch(void* const* d_in, const int* in_sizes, int n_in,
                              void* d_out, int out_size, void* d_ws, size_t ws_size,
                              hipStream_t stream)
{
    const float* q  = (const float*)d_in[0];
    const float* k  = (const float*)d_in[1];
    const float* v  = (const float*)d_in[2];
    const float* wq = (const float*)d_in[3];
    const float* bq = (const float*)d_in[4];
    const float* wk = (const float*)d_in[5];
    const float* bk = (const float*)d_in[6];
    const float* wv = (const float*)d_in[7];
    const float* bv = (const float*)d_in[8];
    const float* wo = (const float*)d_in[9];
    const float* bo = (const float*)d_in[10];

    // d_out (32 MiB) doubles as scratch for Qp+Kp until the final GEMM.
    unsigned short* Qp  = (unsigned short*)d_out;
    unsigned short* Kp  = Qp + (size_t)MROWS*EMBED;
    unsigned short* Vt  = (unsigned short*)d_ws;           // [b][h][d][s]
    unsigned short* ctx = Vt + (size_t)MROWS*EMBED;
    float* out = (float*)d_out;

    dim3 g(MROWS/128, EMBED/128), tpb(256);
    gemm_xwT<0,0><<<g, tpb, 0, stream>>>(q, wq, bq, Qp);
    gemm_xwT<0,0><<<g, tpb, 0, stream>>>(k, wk, bk, Kp);
    gemm_xwT<0,1><<<g, tpb, 0, stream>>>(v, wv, bv, Vt);
    attn_fwd<<<dim3(SEQ/64, NB*NH), tpb, 0, stream>>>(Qp, Kp, Vt, ctx);
    gemm_xwT<1,2><<<g, tpb, 0, stream>>>(ctx, wo, bo, out);
}

// Round 2
// 300.969 us; speedup vs baseline: 1.9600x; 1.9600x over previous
//
#include <hip/hip_runtime.h>
#include <hip/hip_bf16.h>

#define EMBED 1024
#define SEQ   2048
#define NB    4
#define NH    16
#define HD    64
#define MROWS (NB*SEQ)   // 8192

typedef __attribute__((ext_vector_type(4))) float  f32x4;
typedef __attribute__((ext_vector_type(8))) short  s16x8;

#define MFMA16(a,b,c) __builtin_amdgcn_mfma_f32_16x16x32_bf16((a),(b),(c),0,0,0)

__device__ __forceinline__ unsigned short f2bf(float f) {
    union { float f; unsigned int u; } v; v.f = f;
    unsigned int r = v.u + 0x7fffu + ((v.u >> 16) & 1u);   // RTNE
    return (unsigned short)(r >> 16);
}
__device__ __forceinline__ unsigned int pack2(float a, float b) {
    return (unsigned int)f2bf(a) | ((unsigned int)f2bf(b) << 16);
}
// XOR-swizzled byte offset into a [rows][64-short] LDS tile (128B rows).
__device__ __forceinline__ int swz(int row, int colb) {
    return row*128 + (colb ^ ((row & 7) << 4));
}

// ---------------------------------------------------------------------------
// GEMM: Y[m,n] = sum_k A[m,k] * W[n,k] + bias[n]   (unchanged from R0)
// ---------------------------------------------------------------------------
template<int AMODE, int OMODE>
__global__ __launch_bounds__(256) void gemm_xwT(
    const void* __restrict__ Ap, const float* __restrict__ W,
    const float* __restrict__ bias, void* __restrict__ Yp)
{
    __shared__ unsigned short Ald[128*72];
    __shared__ unsigned short Bld[128*72];
    const int t   = threadIdx.x;
    const int bm  = blockIdx.x, bn = blockIdx.y;
    const int wid = t >> 6, lane = t & 63, l15 = lane & 15, blk = lane >> 4;
    const int wr  = wid >> 1, wc = wid & 1;

    const float*          Af = (const float*)Ap;
    const unsigned short* Ab = (const unsigned short*)Ap;

    f32x4 acc[4][4] = {};

    for (int kt = 0; kt < EMBED/64; ++kt) {
        if (AMODE == 0) {
            #pragma unroll
            for (int i = 0; i < 8; ++i) {
                int f = t + 256*i, row = f >> 4, c4 = f & 15;
                float4 v = *(const float4*)(Af + (size_t)(bm*128+row)*EMBED + kt*64 + c4*4);
                *(uint2*)&Ald[row*72 + c4*4] = make_uint2(pack2(v.x,v.y), pack2(v.z,v.w));
            }
        } else {
            #pragma unroll
            for (int i = 0; i < 4; ++i) {
                int f = t + 256*i, row = f >> 3, c8 = f & 7;
                *(s16x8*)&Ald[row*72 + c8*8] =
                    *(const s16x8*)(Ab + (size_t)(bm*128+row)*EMBED + kt*64 + c8*8);
            }
        }
        #pragma unroll
        for (int i = 0; i < 8; ++i) {
            int f = t + 256*i, row = f >> 4, c4 = f & 15;
            float4 v = *(const float4*)(W + (size_t)(bn*128+row)*EMBED + kt*64 + c4*4);
            *(uint2*)&Bld[row*72 + c4*4] = make_uint2(pack2(v.x,v.y), pack2(v.z,v.w));
        }
        __syncthreads();
        #pragma unroll
        for (int ks = 0; ks < 2; ++ks) {
            s16x8 af[4], bf[4];
            #pragma unroll
            for (int mt = 0; mt < 4; ++mt)
                af[mt] = *(const s16x8*)&Ald[(wr*64 + mt*16 + l15)*72 + ks*32 + blk*8];
            #pragma unroll
            for (int nt = 0; nt < 4; ++nt)
                bf[nt] = *(const s16x8*)&Bld[(wc*64 + nt*16 + l15)*72 + ks*32 + blk*8];
            #pragma unroll
            for (int mt = 0; mt < 4; ++mt)
                #pragma unroll
                for (int nt = 0; nt < 4; ++nt)
                    acc[mt][nt] = MFMA16(af[mt], bf[nt], acc[mt][nt]);
        }
        __syncthreads();
    }

    float bv[4];
    #pragma unroll
    for (int nt = 0; nt < 4; ++nt)
        bv[nt] = bias[bn*128 + wc*64 + nt*16 + l15];

    unsigned short* Yb = (unsigned short*)Yp;
    float*          Yf = (float*)Yp;

    #pragma unroll
    for (int mt = 0; mt < 4; ++mt) {
        #pragma unroll
        for (int nt = 0; nt < 4; ++nt) {
            const int m0 = bm*128 + wr*64 + mt*16 + blk*4;
            const int n  = bn*128 + wc*64 + nt*16 + l15;
            f32x4 a = acc[mt][nt];
            if (OMODE == 2) {
                #pragma unroll
                for (int r = 0; r < 4; ++r)
                    Yf[(size_t)(m0+r)*EMBED + n] = a[r] + bv[nt];
            } else if (OMODE == 0) {
                #pragma unroll
                for (int r = 0; r < 4; ++r)
                    Yb[(size_t)(m0+r)*EMBED + n] = f2bf(a[r] + bv[nt]);
            } else {
                const int b = m0 >> 11, s = m0 & (SEQ-1);
                const int h = n >> 6,  d = n & (HD-1);
                ushort4 pk;
                pk.x = f2bf(a[0] + bv[nt]); pk.y = f2bf(a[1] + bv[nt]);
                pk.z = f2bf(a[2] + bv[nt]); pk.w = f2bf(a[3] + bv[nt]);
                *(ushort4*)&Yb[(((size_t)b*NH + h)*HD + d)*SEQ + s] = pk;
            }
        }
    }
}

// ---------------------------------------------------------------------------
// Flash attention v2.
//  - 1 block = one (b,h) x 128 q-rows; 4 waves x 32 q-rows each.
//  - KVBLK=64: K[64][64] and V^T[64][64] reg-staged into XOR-swizzled LDS,
//    shared by all waves; loads for tile t+1 issued before compute(t) (T14).
//  - Swapped QK^T (mfma(K,Q)): lane owns q=lane&15; softmax reduce = 2 shfl.
//  - P repacked via per-wave swizzled LDS roundtrip into PV A-fragments.
//  - grid.x = bh  -> all q-blocks of a head land on XCD bh%8 (L2 locality).
// ---------------------------------------------------------------------------
__global__ __launch_bounds__(256) void attn_fwd(
    const unsigned short* __restrict__ Qp,
    const unsigned short* __restrict__ Kp,
    const unsigned short* __restrict__ Vt,
    unsigned short* __restrict__ ctx)
{
    __shared__ unsigned short Kld[64*64];     // [k][d]   swizzled
    __shared__ unsigned short Vld[64*64];     // [d][k]   swizzled
    __shared__ unsigned short Pld[4][32*64];  // per-wave [q][k] swizzled

    const int t = threadIdx.x, wid = t >> 6, lane = t & 63;
    const int l15 = lane & 15, blk = lane >> 4;
    const int bh = blockIdx.x, qb = blockIdx.y;
    const int b = bh >> 4, h = bh & (NH-1);
    const int q0 = qb*128 + wid*32;

    // Q fragments (B-operand: col=q=l15, k=d)
    s16x8 qf[2][2];
    #pragma unroll
    for (int qs = 0; qs < 2; ++qs) {
        const unsigned short* qp = Qp + (size_t)(b*SEQ + q0 + qs*16 + l15)*EMBED + h*HD;
        qf[qs][0] = *(const s16x8*)(qp + blk*8);
        qf[qs][1] = *(const s16x8*)(qp + 32 + blk*8);
    }

    const unsigned short* kb = Kp + (size_t)b*SEQ*EMBED + h*HD;
    const unsigned short* vb = Vt + (size_t)bh*HD*SEQ;

    // staging: thread covers rows srow and srow+32, 16B each
    const int srow = t >> 3, scolb = (t & 7)*16;
    const unsigned short* kg0 = kb + (size_t)srow*EMBED + scolb/2;
    const unsigned short* kg1 = kb + (size_t)(srow+32)*EMBED + scolb/2;
    const unsigned short* vg0 = vb + (size_t)srow*SEQ + scolb/2;
    const unsigned short* vg1 = vb + (size_t)(srow+32)*SEQ + scolb/2;
    const int w0 = swz(srow, scolb), w1 = swz(srow+32, scolb);

    unsigned short* pl = &Pld[wid][0];
    // hoisted swizzled column offsets for reads
    const int rc0 = (blk*16) ^ ((l15 & 7) << 4);   // ks=0
    const int rc1 = rc0 ^ 64;                      // ks=1

    f32x4 o[2][4] = {};
    float m2[2] = {-1e30f, -1e30f}, lsum[2] = {0.f, 0.f};
    const float sc2 = 0.125f * 1.44269504088896f;  // 1/sqrt(64) * log2(e)

    s16x8 kr0 = *(const s16x8*)kg0;
    s16x8 kr1 = *(const s16x8*)kg1;
    s16x8 vr0 = *(const s16x8*)vg0;
    s16x8 vr1 = *(const s16x8*)vg1;

    for (int tt = 0; tt < SEQ/64; ++tt) {
        __syncthreads();                       // prev tile's LDS reads done
        *(s16x8*)((char*)Kld + w0) = kr0;
        *(s16x8*)((char*)Kld + w1) = kr1;
        *(s16x8*)((char*)Vld + w0) = vr0;
        *(s16x8*)((char*)Vld + w1) = vr1;
        __syncthreads();                       // tile ready
        if (tt + 1 < SEQ/64) {                 // issue next-tile loads early
            const size_t ko = (size_t)(tt+1)*64;
            kr0 = *(const s16x8*)(kg0 + ko*EMBED);
            kr1 = *(const s16x8*)(kg1 + ko*EMBED);
            vr0 = *(const s16x8*)(vg0 + ko);
            vr1 = *(const s16x8*)(vg1 + ko);
        }

        // ---- QK^T: sc[qs][kt], lane: q=l15, k=kt*16+blk*4+r ----
        f32x4 sc[2][4];
        #pragma unroll
        for (int qs = 0; qs < 2; ++qs)
            #pragma unroll
            for (int kt = 0; kt < 4; ++kt)
                sc[qs][kt] = f32x4{0.f,0.f,0.f,0.f};
        #pragma unroll
        for (int kt = 0; kt < 4; ++kt) {
            const char* krow = (const char*)Kld + (kt*16 + l15)*128;
            s16x8 ka0 = *(const s16x8*)(krow + rc0);
            s16x8 ka1 = *(const s16x8*)(krow + rc1);
            #pragma unroll
            for (int qs = 0; qs < 2; ++qs) {
                sc[qs][kt] = MFMA16(ka0, qf[qs][0], sc[qs][kt]);
                sc[qs][kt] = MFMA16(ka1, qf[qs][1], sc[qs][kt]);
            }
        }

        // ---- online softmax + P write + O rescale ----
        #pragma unroll
        for (int qs = 0; qs < 2; ++qs) {
            float pm = sc[qs][0][0];
            #pragma unroll
            for (int kt = 0; kt < 4; ++kt)
                #pragma unroll
                for (int r = 0; r < 4; ++r)
                    pm = fmaxf(pm, sc[qs][kt][r]);
            pm = fmaxf(pm, __shfl_xor(pm, 16));
            pm = fmaxf(pm, __shfl_xor(pm, 32));
            const float mn = fmaxf(m2[qs], pm * sc2);
            const float al = exp2f(m2[qs] - mn);
            m2[qs] = mn;
            float ps = 0.f;
            #pragma unroll
            for (int kt = 0; kt < 4; ++kt) {
                const float p0 = exp2f(sc[qs][kt][0]*sc2 - mn);
                const float p1 = exp2f(sc[qs][kt][1]*sc2 - mn);
                const float p2 = exp2f(sc[qs][kt][2]*sc2 - mn);
                const float p3 = exp2f(sc[qs][kt][3]*sc2 - mn);
                ps += (p0+p1) + (p2+p3);
                const int off = (qs*16 + l15)*128 + (((kt*32 + blk*8)) ^ ((l15 & 7) << 4));
                *(uint2*)((char*)pl + off) = make_uint2(pack2(p0,p1), pack2(p2,p3));
            }
            ps += __shfl_xor(ps, 16);
            ps += __shfl_xor(ps, 32);
            lsum[qs] = lsum[qs]*al + ps;
            float ar[4];
            #pragma unroll
            for (int r = 0; r < 4; ++r) ar[r] = __shfl(al, blk*4 + r);
            #pragma unroll
            for (int dt = 0; dt < 4; ++dt)
                #pragma unroll
                for (int r = 0; r < 4; ++r) o[qs][dt][r] *= ar[r];
        }

        // ---- PV: A = P[q][k] (row=q=l15), B = V^T[d][k] (col=d) ----
        s16x8 pa[2][2];
        #pragma unroll
        for (int qs = 0; qs < 2; ++qs) {
            const char* prow = (const char*)pl + (qs*16 + l15)*128;
            pa[qs][0] = *(const s16x8*)(prow + rc0);
            pa[qs][1] = *(const s16x8*)(prow + rc1);
        }
        #pragma unroll
        for (int dt = 0; dt < 4; ++dt) {
            const char* vrow = (const char*)Vld + (dt*16 + l15)*128;
            s16x8 vb0 = *(const s16x8*)(vrow + rc0);
            s16x8 vb1 = *(const s16x8*)(vrow + rc1);
            #pragma unroll
            for (int qs = 0; qs < 2; ++qs) {
                o[qs][dt] = MFMA16(pa[qs][0], vb0, o[qs][dt]);
                o[qs][dt] = MFMA16(pa[qs][1], vb1, o[qs][dt]);
            }
        }
    }

    // ---- epilogue ----
    #pragma unroll
    for (int qs = 0; qs < 2; ++qs) {
        float li[4];
        #pragma unroll
        for (int r = 0; r < 4; ++r) li[r] = 1.f / __shfl(lsum[qs], blk*4 + r);
        unsigned short* cp = ctx + (size_t)(b*SEQ + q0 + qs*16)*EMBED + h*HD;
        #pragma unroll
        for (int dt = 0; dt < 4; ++dt)
            #pragma unroll
            for (int r = 0; r < 4; ++r)
                cp[(size_t)(blk*4 + r)*EMBED + dt*16 + l15] = f2bf(o[qs][dt][r] * li[r]);
    }
}

// ---------------------------------------------------------------------------
extern "C" void kernel_launch(void* const* d_in, const int* in_sizes, int n_in,
                              void* d_out, int out_size, void* d_ws, size_t ws_size,
                              hipStream_t stream)
{
    const float* q  = (const float*)d_in[0];
    const float* k  = (const float*)d_in[1];
    const float* v  = (const float*)d_in[2];
    const float* wq = (const float*)d_in[3];
    const float* bq = (const float*)d_in[4];
    const float* wk = (const float*)d_in[5];
    const float* bk = (const float*)d_in[6];
    const float* wv = (const float*)d_in[7];
    const float* bv = (const float*)d_in[8];
    const float* wo = (const float*)d_in[9];
    const float* bo = (const float*)d_in[10];

    unsigned short* Qp  = (unsigned short*)d_out;          // d_out as scratch
    unsigned short* Kp  = Qp + (size_t)MROWS*EMBED;
    unsigned short* Vt  = (unsigned short*)d_ws;           // [b][h][d][s]
    unsigned short* ctx = Vt + (size_t)MROWS*EMBED;
    float* out = (float*)d_out;

    dim3 g(MROWS/128, EMBED/128), tpb(256);
    gemm_xwT<0,0><<<g, tpb, 0, stream>>>(q, wq, bq, Qp);
    gemm_xwT<0,0><<<g, tpb, 0, stream>>>(k, wk, bk, Kp);
    gemm_xwT<0,1><<<g, tpb, 0, stream>>>(v, wv, bv, Vt);
    attn_fwd<<<dim3(NB*NH, SEQ/128), tpb, 0, stream>>>(Qp, Kp, Vt, ctx);
    gemm_xwT<1,2><<<g, tpb, 0, stream>>>(ctx, wo, bo, out);
}

// Round 3
// 267.274 us; speedup vs baseline: 2.2071x; 1.1261x over previous
//
#include <hip/hip_runtime.h>
#include <hip/hip_bf16.h>

#define EMBED 1024
#define SEQ   2048
#define NB    4
#define NH    16
#define HD    64
#define MROWS (NB*SEQ)   // 8192

typedef __attribute__((ext_vector_type(4))) float  f32x4;
typedef __attribute__((ext_vector_type(8))) short  s16x8;

#define MFMA16(a,b,c) __builtin_amdgcn_mfma_f32_16x16x32_bf16((a),(b),(c),0,0,0)

__device__ __forceinline__ unsigned short f2bf(float f) {
    union { float f; unsigned int u; } v; v.f = f;
    unsigned int r = v.u + 0x7fffu + ((v.u >> 16) & 1u);   // RTNE
    return (unsigned short)(r >> 16);
}
// HW packed fp32->bf16 (RTNE), 1 VALU inst for 2 values.
__device__ __forceinline__ unsigned int cvtpk(float a, float b) {
    unsigned int r;
    asm("v_cvt_pk_bf16_f32 %0, %1, %2" : "=v"(r) : "v"(a), "v"(b));
    return r;
}
// XOR-swizzled byte offset into a [rows][64-short] LDS tile (128B rows).
__device__ __forceinline__ int swz(int row, int colb) {
    return row*128 + (colb ^ ((row & 7) << 4));
}

#define SC2 0.18033688f   // (1/sqrt(64)) * log2(e)

// ---------------------------------------------------------------------------
// GEMM: Y[m,n] = sum_k A[m,k] * W[n,k] + bias[n]
//   AMODE 0: A fp32 (cvt_pk while staging). AMODE 1: A bf16.
//   OMODE 0: bf16 row-major; OMODE 1: bf16 V^T per head [b][h][d][s];
//   OMODE 2: fp32 row-major.
//   SCALEQ: multiply output by SC2 (folds softmax scale into Q-projection).
// ---------------------------------------------------------------------------
template<int AMODE, int OMODE, int SCALEQ>
__global__ __launch_bounds__(256) void gemm_xwT(
    const void* __restrict__ Ap, const float* __restrict__ W,
    const float* __restrict__ bias, void* __restrict__ Yp)
{
    __shared__ unsigned short Ald[128*72];
    __shared__ unsigned short Bld[128*72];
    const int t   = threadIdx.x;
    const int bm  = blockIdx.x, bn = blockIdx.y;
    const int wid = t >> 6, lane = t & 63, l15 = lane & 15, blk = lane >> 4;
    const int wr  = wid >> 1, wc = wid & 1;

    const float*          Af = (const float*)Ap;
    const unsigned short* Ab = (const unsigned short*)Ap;

    f32x4 acc[4][4] = {};

    for (int kt = 0; kt < EMBED/64; ++kt) {
        if (AMODE == 0) {
            #pragma unroll
            for (int i = 0; i < 8; ++i) {
                int f = t + 256*i, row = f >> 4, c4 = f & 15;
                float4 v = *(const float4*)(Af + (size_t)(bm*128+row)*EMBED + kt*64 + c4*4);
                *(uint2*)&Ald[row*72 + c4*4] = make_uint2(cvtpk(v.x,v.y), cvtpk(v.z,v.w));
            }
        } else {
            #pragma unroll
            for (int i = 0; i < 4; ++i) {
                int f = t + 256*i, row = f >> 3, c8 = f & 7;
                *(s16x8*)&Ald[row*72 + c8*8] =
                    *(const s16x8*)(Ab + (size_t)(bm*128+row)*EMBED + kt*64 + c8*8);
            }
        }
        #pragma unroll
        for (int i = 0; i < 8; ++i) {
            int f = t + 256*i, row = f >> 4, c4 = f & 15;
            float4 v = *(const float4*)(W + (size_t)(bn*128+row)*EMBED + kt*64 + c4*4);
            *(uint2*)&Bld[row*72 + c4*4] = make_uint2(cvtpk(v.x,v.y), cvtpk(v.z,v.w));
        }
        __syncthreads();
        #pragma unroll
        for (int ks = 0; ks < 2; ++ks) {
            s16x8 af[4], bf[4];
            #pragma unroll
            for (int mt = 0; mt < 4; ++mt)
                af[mt] = *(const s16x8*)&Ald[(wr*64 + mt*16 + l15)*72 + ks*32 + blk*8];
            #pragma unroll
            for (int nt = 0; nt < 4; ++nt)
                bf[nt] = *(const s16x8*)&Bld[(wc*64 + nt*16 + l15)*72 + ks*32 + blk*8];
            #pragma unroll
            for (int mt = 0; mt < 4; ++mt)
                #pragma unroll
                for (int nt = 0; nt < 4; ++nt)
                    acc[mt][nt] = MFMA16(af[mt], bf[nt], acc[mt][nt]);
        }
        __syncthreads();
    }

    float bv[4];
    #pragma unroll
    for (int nt = 0; nt < 4; ++nt)
        bv[nt] = bias[bn*128 + wc*64 + nt*16 + l15];

    unsigned short* Yb = (unsigned short*)Yp;
    float*          Yf = (float*)Yp;

    #pragma unroll
    for (int mt = 0; mt < 4; ++mt) {
        #pragma unroll
        for (int nt = 0; nt < 4; ++nt) {
            const int m0 = bm*128 + wr*64 + mt*16 + blk*4;
            const int n  = bn*128 + wc*64 + nt*16 + l15;
            f32x4 a = acc[mt][nt];
            if (OMODE == 2) {
                #pragma unroll
                for (int r = 0; r < 4; ++r)
                    Yf[(size_t)(m0+r)*EMBED + n] = a[r] + bv[nt];
            } else if (OMODE == 0) {
                #pragma unroll
                for (int r = 0; r < 4; ++r) {
                    float val = a[r] + bv[nt];
                    if (SCALEQ) val *= SC2;
                    Yb[(size_t)(m0+r)*EMBED + n] = f2bf(val);
                }
            } else {
                const int b = m0 >> 11, s = m0 & (SEQ-1);
                const int h = n >> 6,  d = n & (HD-1);
                ushort4 pk;
                pk.x = f2bf(a[0] + bv[nt]); pk.y = f2bf(a[1] + bv[nt]);
                pk.z = f2bf(a[2] + bv[nt]); pk.w = f2bf(a[3] + bv[nt]);
                *(ushort4*)&Yb[(((size_t)b*NH + h)*HD + d)*SEQ + s] = pk;
            }
        }
    }
}

// ---------------------------------------------------------------------------
// Flash attention v3.
//  - Q pre-scaled by SC2 in its projection -> scores already in exp2 domain.
//  - Defer-max (T13, THR=8): skip O-rescale while the running max holds.
//  - P -> bf16 via v_cvt_pk_bf16_f32 (T12).
//  - Structure as v2: KVBLK=64 in XOR-swizzled LDS, swapped QK^T, 4w x 32q.
// ---------------------------------------------------------------------------
__global__ __launch_bounds__(256) void attn_fwd(
    const unsigned short* __restrict__ Qp,
    const unsigned short* __restrict__ Kp,
    const unsigned short* __restrict__ Vt,
    unsigned short* __restrict__ ctx)
{
    __shared__ unsigned short Kld[64*64];     // [k][d]   swizzled
    __shared__ unsigned short Vld[64*64];     // [d][k]   swizzled
    __shared__ unsigned short Pld[4][32*64];  // per-wave [q][k] swizzled

    const int t = threadIdx.x, wid = t >> 6, lane = t & 63;
    const int l15 = lane & 15, blk = lane >> 4;
    const int bh = blockIdx.x, qb = blockIdx.y;
    const int b = bh >> 4, h = bh & (NH-1);
    const int q0 = qb*128 + wid*32;

    s16x8 qf[2][2];
    #pragma unroll
    for (int qs = 0; qs < 2; ++qs) {
        const unsigned short* qp = Qp + (size_t)(b*SEQ + q0 + qs*16 + l15)*EMBED + h*HD;
        qf[qs][0] = *(const s16x8*)(qp + blk*8);
        qf[qs][1] = *(const s16x8*)(qp + 32 + blk*8);
    }

    const unsigned short* kb = Kp + (size_t)b*SEQ*EMBED + h*HD;
    const unsigned short* vb = Vt + (size_t)bh*HD*SEQ;

    const int srow = t >> 3, scolb = (t & 7)*16;
    const unsigned short* kg0 = kb + (size_t)srow*EMBED + scolb/2;
    const unsigned short* kg1 = kb + (size_t)(srow+32)*EMBED + scolb/2;
    const unsigned short* vg0 = vb + (size_t)srow*SEQ + scolb/2;
    const unsigned short* vg1 = vb + (size_t)(srow+32)*SEQ + scolb/2;
    const int w0 = swz(srow, scolb), w1 = swz(srow+32, scolb);

    unsigned short* pl = &Pld[wid][0];
    const int rc0 = (blk*16) ^ ((l15 & 7) << 4);
    const int rc1 = rc0 ^ 64;

    f32x4 o[2][4] = {};
    float m2[2] = {-1e30f, -1e30f}, lsum[2] = {0.f, 0.f};

    s16x8 kr0 = *(const s16x8*)kg0;
    s16x8 kr1 = *(const s16x8*)kg1;
    s16x8 vr0 = *(const s16x8*)vg0;
    s16x8 vr1 = *(const s16x8*)vg1;

    for (int tt = 0; tt < SEQ/64; ++tt) {
        __syncthreads();
        *(s16x8*)((char*)Kld + w0) = kr0;
        *(s16x8*)((char*)Kld + w1) = kr1;
        *(s16x8*)((char*)Vld + w0) = vr0;
        *(s16x8*)((char*)Vld + w1) = vr1;
        __syncthreads();
        if (tt + 1 < SEQ/64) {
            const size_t ko = (size_t)(tt+1)*64;
            kr0 = *(const s16x8*)(kg0 + ko*EMBED);
            kr1 = *(const s16x8*)(kg1 + ko*EMBED);
            vr0 = *(const s16x8*)(vg0 + ko);
            vr1 = *(const s16x8*)(vg1 + ko);
        }

        // ---- QK^T (already exp2-domain scaled) ----
        f32x4 sc[2][4];
        #pragma unroll
        for (int qs = 0; qs < 2; ++qs)
            #pragma unroll
            for (int kt = 0; kt < 4; ++kt)
                sc[qs][kt] = f32x4{0.f,0.f,0.f,0.f};
        #pragma unroll
        for (int kt = 0; kt < 4; ++kt) {
            const char* krow = (const char*)Kld + (kt*16 + l15)*128;
            s16x8 ka0 = *(const s16x8*)(krow + rc0);
            s16x8 ka1 = *(const s16x8*)(krow + rc1);
            #pragma unroll
            for (int qs = 0; qs < 2; ++qs) {
                sc[qs][kt] = MFMA16(ka0, qf[qs][0], sc[qs][kt]);
                sc[qs][kt] = MFMA16(ka1, qf[qs][1], sc[qs][kt]);
            }
        }

        // ---- online softmax (defer-max) + P pack ----
        #pragma unroll
        for (int qs = 0; qs < 2; ++qs) {
            float pm = sc[qs][0][0];
            #pragma unroll
            for (int kt = 0; kt < 4; ++kt)
                #pragma unroll
                for (int r = 0; r < 4; ++r)
                    pm = fmaxf(pm, sc[qs][kt][r]);
            pm = fmaxf(pm, __shfl_xor(pm, 16));
            pm = fmaxf(pm, __shfl_xor(pm, 32));

            float al = 1.f;
            if (!__all(pm <= m2[qs] + 8.f)) {          // rare rescale path
                const float mn = fmaxf(m2[qs], pm);
                al = exp2f(m2[qs] - mn);
                m2[qs] = mn;
                float ar[4];
                #pragma unroll
                for (int r = 0; r < 4; ++r) ar[r] = __shfl(al, blk*4 + r);
                #pragma unroll
                for (int dt = 0; dt < 4; ++dt)
                    #pragma unroll
                    for (int r = 0; r < 4; ++r) o[qs][dt][r] *= ar[r];
            }
            const float mn = m2[qs];
            float ps = 0.f;
            #pragma unroll
            for (int kt = 0; kt < 4; ++kt) {
                const float p0 = exp2f(sc[qs][kt][0] - mn);
                const float p1 = exp2f(sc[qs][kt][1] - mn);
                const float p2 = exp2f(sc[qs][kt][2] - mn);
                const float p3 = exp2f(sc[qs][kt][3] - mn);
                ps += (p0+p1) + (p2+p3);
                const int off = (qs*16 + l15)*128 + ((kt*32 + blk*8) ^ ((l15 & 7) << 4));
                *(uint2*)((char*)pl + off) = make_uint2(cvtpk(p0,p1), cvtpk(p2,p3));
            }
            ps += __shfl_xor(ps, 16);
            ps += __shfl_xor(ps, 32);
            lsum[qs] = lsum[qs]*al + ps;
        }

        // ---- PV ----
        s16x8 pa[2][2];
        #pragma unroll
        for (int qs = 0; qs < 2; ++qs) {
            const char* prow = (const char*)pl + (qs*16 + l15)*128;
            pa[qs][0] = *(const s16x8*)(prow + rc0);
            pa[qs][1] = *(const s16x8*)(prow + rc1);
        }
        #pragma unroll
        for (int dt = 0; dt < 4; ++dt) {
            const char* vrow = (const char*)Vld + (dt*16 + l15)*128;
            s16x8 vb0 = *(const s16x8*)(vrow + rc0);
            s16x8 vb1 = *(const s16x8*)(vrow + rc1);
            #pragma unroll
            for (int qs = 0; qs < 2; ++qs) {
                o[qs][dt] = MFMA16(pa[qs][0], vb0, o[qs][dt]);
                o[qs][dt] = MFMA16(pa[qs][1], vb1, o[qs][dt]);
            }
        }
    }

    #pragma unroll
    for (int qs = 0; qs < 2; ++qs) {
        float li[4];
        #pragma unroll
        for (int r = 0; r < 4; ++r) li[r] = 1.f / __shfl(lsum[qs], blk*4 + r);
        unsigned short* cp = ctx + (size_t)(b*SEQ + q0 + qs*16)*EMBED + h*HD;
        #pragma unroll
        for (int dt = 0; dt < 4; ++dt)
            #pragma unroll
            for (int r = 0; r < 4; ++r)
                cp[(size_t)(blk*4 + r)*EMBED + dt*16 + l15] = f2bf(o[qs][dt][r] * li[r]);
    }
}

// ---------------------------------------------------------------------------
extern "C" void kernel_launch(void* const* d_in, const int* in_sizes, int n_in,
                              void* d_out, int out_size, void* d_ws, size_t ws_size,
                              hipStream_t stream)
{
    const float* q  = (const float*)d_in[0];
    const float* k  = (const float*)d_in[1];
    const float* v  = (const float*)d_in[2];
    const float* wq = (const float*)d_in[3];
    const float* bq = (const float*)d_in[4];
    const float* wk = (const float*)d_in[5];
    const float* bk = (const float*)d_in[6];
    const float* wv = (const float*)d_in[7];
    const float* bv = (const float*)d_in[8];
    const float* wo = (const float*)d_in[9];
    const float* bo = (const float*)d_in[10];

    unsigned short* Qp  = (unsigned short*)d_out;          // d_out as scratch
    unsigned short* Kp  = Qp + (size_t)MROWS*EMBED;
    unsigned short* Vt  = (unsigned short*)d_ws;           // [b][h][d][s]
    unsigned short* ctx = Vt + (size_t)MROWS*EMBED;
    float* out = (float*)d_out;

    dim3 g(MROWS/128, EMBED/128), tpb(256);
    gemm_xwT<0,0,1><<<g, tpb, 0, stream>>>(q, wq, bq, Qp);   // Q, pre-scaled
    gemm_xwT<0,0,0><<<g, tpb, 0, stream>>>(k, wk, bk, Kp);
    gemm_xwT<0,1,0><<<g, tpb, 0, stream>>>(v, wv, bv, Vt);
    attn_fwd<<<dim3(NB*NH, SEQ/128), tpb, 0, stream>>>(Qp, Kp, Vt, ctx);
    gemm_xwT<1,2,0><<<g, tpb, 0, stream>>>(ctx, wo, bo, out);
}

// Round 4
// 255.498 us; speedup vs baseline: 2.3088x; 1.0461x over previous
//
#include <hip/hip_runtime.h>
#include <hip/hip_bf16.h>

#define EMBED 1024
#define SEQ   2048
#define NB    4
#define NH    16
#define HD    64
#define MROWS (NB*SEQ)   // 8192

typedef __attribute__((ext_vector_type(4))) float  f32x4;
typedef __attribute__((ext_vector_type(8))) short  s16x8;

#define MFMA16(a,b,c) __builtin_amdgcn_mfma_f32_16x16x32_bf16((a),(b),(c),0,0,0)

__device__ __forceinline__ unsigned short f2bf(float f) {
    union { float f; unsigned int u; } v; v.f = f;
    unsigned int r = v.u + 0x7fffu + ((v.u >> 16) & 1u);   // RTNE
    return (unsigned short)(r >> 16);
}
__device__ __forceinline__ unsigned int cvtpk(float a, float b) {
    unsigned int r;
    asm("v_cvt_pk_bf16_f32 %0, %1, %2" : "=v"(r) : "v"(a), "v"(b));
    return r;
}
__device__ __forceinline__ float max3f(float a, float b, float c) {
    float r;
    asm("v_max3_f32 %0, %1, %2, %3" : "=v"(r) : "v"(a), "v"(b), "v"(c));
    return r;
}
__device__ __forceinline__ int swz(int row, int colb) {
    return row*128 + (colb ^ ((row & 7) << 4));
}

#define SC2 0.18033688f   // (1/sqrt(64)) * log2(e)

// ---------------------------------------------------------------------------
// Projection GEMM: Y = A W^T + b.  OMODE 0: bf16 row-major (SCALE applied);
// OMODE 1: bf16 Vt[b][h][d][s].  A is fp32, converted while staging.
// ---------------------------------------------------------------------------
template<int OMODE, int SCALEQ>
__global__ __launch_bounds__(256) void gemm_proj(
    const float* __restrict__ Af, const float* __restrict__ W,
    const float* __restrict__ bias, unsigned short* __restrict__ Yb)
{
    __shared__ unsigned short Ald[128*72];
    __shared__ unsigned short Bld[128*72];
    const int t   = threadIdx.x;
    const int bm  = blockIdx.x, bn = blockIdx.y;
    const int wid = t >> 6, lane = t & 63, l15 = lane & 15, blk = lane >> 4;
    const int wr  = wid >> 1, wc = wid & 1;

    f32x4 acc[4][4] = {};

    for (int kt = 0; kt < EMBED/64; ++kt) {
        #pragma unroll
        for (int i = 0; i < 8; ++i) {
            int f = t + 256*i, row = f >> 4, c4 = f & 15;
            float4 v = *(const float4*)(Af + (size_t)(bm*128+row)*EMBED + kt*64 + c4*4);
            *(uint2*)&Ald[row*72 + c4*4] = make_uint2(cvtpk(v.x,v.y), cvtpk(v.z,v.w));
        }
        #pragma unroll
        for (int i = 0; i < 8; ++i) {
            int f = t + 256*i, row = f >> 4, c4 = f & 15;
            float4 v = *(const float4*)(W + (size_t)(bn*128+row)*EMBED + kt*64 + c4*4);
            *(uint2*)&Bld[row*72 + c4*4] = make_uint2(cvtpk(v.x,v.y), cvtpk(v.z,v.w));
        }
        __syncthreads();
        #pragma unroll
        for (int ks = 0; ks < 2; ++ks) {
            s16x8 af[4], bf[4];
            #pragma unroll
            for (int mt = 0; mt < 4; ++mt)
                af[mt] = *(const s16x8*)&Ald[(wr*64 + mt*16 + l15)*72 + ks*32 + blk*8];
            #pragma unroll
            for (int nt = 0; nt < 4; ++nt)
                bf[nt] = *(const s16x8*)&Bld[(wc*64 + nt*16 + l15)*72 + ks*32 + blk*8];
            #pragma unroll
            for (int mt = 0; mt < 4; ++mt)
                #pragma unroll
                for (int nt = 0; nt < 4; ++nt)
                    acc[mt][nt] = MFMA16(af[mt], bf[nt], acc[mt][nt]);
        }
        __syncthreads();
    }

    float bv4[4];
    #pragma unroll
    for (int nt = 0; nt < 4; ++nt)
        bv4[nt] = bias[bn*128 + wc*64 + nt*16 + l15];

    #pragma unroll
    for (int mt = 0; mt < 4; ++mt) {
        #pragma unroll
        for (int nt = 0; nt < 4; ++nt) {
            const int m0 = bm*128 + wr*64 + mt*16 + blk*4;
            const int n  = bn*128 + wc*64 + nt*16 + l15;
            f32x4 a = acc[mt][nt];
            if (OMODE == 0) {
                #pragma unroll
                for (int r = 0; r < 4; ++r) {
                    float val = a[r] + bv4[nt];
                    if (SCALEQ) val *= SC2;
                    Yb[(size_t)(m0+r)*EMBED + n] = f2bf(val);
                }
            } else {
                const int b = m0 >> 11, s = m0 & (SEQ-1);
                const int h = n >> 6,  d = n & (HD-1);
                ushort4 pk;
                pk.x = f2bf(a[0] + bv4[nt]); pk.y = f2bf(a[1] + bv4[nt]);
                pk.z = f2bf(a[2] + bv4[nt]); pk.w = f2bf(a[3] + bv4[nt]);
                *(ushort4*)&Yb[(((size_t)b*NH + h)*HD + d)*SEQ + s] = pk;
            }
        }
    }
}

// ---------------------------------------------------------------------------
// Out-projection GEMM (bf16 A, fp32 out)
// ---------------------------------------------------------------------------
__global__ __launch_bounds__(256) void gemm_out(
    const unsigned short* __restrict__ Ab, const float* __restrict__ W,
    const float* __restrict__ bias, float* __restrict__ Yf)
{
    __shared__ unsigned short Ald[128*72];
    __shared__ unsigned short Bld[128*72];
    const int t   = threadIdx.x;
    const int bm  = blockIdx.x, bn = blockIdx.y;
    const int wid = t >> 6, lane = t & 63, l15 = lane & 15, blk = lane >> 4;
    const int wr  = wid >> 1, wc = wid & 1;

    f32x4 acc[4][4] = {};

    for (int kt = 0; kt < EMBED/64; ++kt) {
        #pragma unroll
        for (int i = 0; i < 4; ++i) {
            int f = t + 256*i, row = f >> 3, c8 = f & 7;
            *(s16x8*)&Ald[row*72 + c8*8] =
                *(const s16x8*)(Ab + (size_t)(bm*128+row)*EMBED + kt*64 + c8*8);
        }
        #pragma unroll
        for (int i = 0; i < 8; ++i) {
            int f = t + 256*i, row = f >> 4, c4 = f & 15;
            float4 v = *(const float4*)(W + (size_t)(bn*128+row)*EMBED + kt*64 + c4*4);
            *(uint2*)&Bld[row*72 + c4*4] = make_uint2(cvtpk(v.x,v.y), cvtpk(v.z,v.w));
        }
        __syncthreads();
        #pragma unroll
        for (int ks = 0; ks < 2; ++ks) {
            s16x8 af[4], bf[4];
            #pragma unroll
            for (int mt = 0; mt < 4; ++mt)
                af[mt] = *(const s16x8*)&Ald[(wr*64 + mt*16 + l15)*72 + ks*32 + blk*8];
            #pragma unroll
            for (int nt = 0; nt < 4; ++nt)
                bf[nt] = *(const s16x8*)&Bld[(wc*64 + nt*16 + l15)*72 + ks*32 + blk*8];
            #pragma unroll
            for (int mt = 0; mt < 4; ++mt)
                #pragma unroll
                for (int nt = 0; nt < 4; ++nt)
                    acc[mt][nt] = MFMA16(af[mt], bf[nt], acc[mt][nt]);
        }
        __syncthreads();
    }

    float bv4[4];
    #pragma unroll
    for (int nt = 0; nt < 4; ++nt)
        bv4[nt] = bias[bn*128 + wc*64 + nt*16 + l15];

    #pragma unroll
    for (int mt = 0; mt < 4; ++mt)
        #pragma unroll
        for (int nt = 0; nt < 4; ++nt) {
            const int m0 = bm*128 + wr*64 + mt*16 + blk*4;
            const int n  = bn*128 + wc*64 + nt*16 + l15;
            f32x4 a = acc[mt][nt];
            #pragma unroll
            for (int r = 0; r < 4; ++r)
                Yf[(size_t)(m0+r)*EMBED + n] = a[r] + bv4[nt];
        }
}

// ---------------------------------------------------------------------------
// Flash attention v4 (see round notes): shuffle-free fast path, max3 tree,
// row-sum on MFMA pipe, s_setprio around MFMA clusters.
// ---------------------------------------------------------------------------
__global__ __launch_bounds__(256) void attn_fwd(
    const unsigned short* __restrict__ Qp,
    const unsigned short* __restrict__ Kp,
    const unsigned short* __restrict__ Vt,
    unsigned short* __restrict__ ctx)
{
    __shared__ unsigned short Kld[64*64];
    __shared__ unsigned short Vld[64*64];
    __shared__ unsigned short Pld[4][32*64];

    const int t = threadIdx.x, wid = t >> 6, lane = t & 63;
    const int l15 = lane & 15, blk = lane >> 4;
    const int bh = blockIdx.x, qb = blockIdx.y;
    const int b = bh >> 4, h = bh & (NH-1);
    const int q0 = qb*128 + wid*32;

    s16x8 qf[2][2];
    #pragma unroll
    for (int qs = 0; qs < 2; ++qs) {
        const unsigned short* qp = Qp + (size_t)(b*SEQ + q0 + qs*16 + l15)*EMBED + h*HD;
        qf[qs][0] = *(const s16x8*)(qp + blk*8);
        qf[qs][1] = *(const s16x8*)(qp + 32 + blk*8);
    }

    const unsigned short* kb = Kp + (size_t)b*SEQ*EMBED + h*HD;
    const unsigned short* vb = Vt + (size_t)bh*HD*SEQ;

    const int srow = t >> 3, scolb = (t & 7)*16;
    const unsigned short* kg0 = kb + (size_t)srow*EMBED + scolb/2;
    const unsigned short* kg1 = kb + (size_t)(srow+32)*EMBED + scolb/2;
    const unsigned short* vg0 = vb + (size_t)srow*SEQ + scolb/2;
    const unsigned short* vg1 = vb + (size_t)(srow+32)*SEQ + scolb/2;
    const int w0 = swz(srow, scolb), w1 = swz(srow+32, scolb);

    unsigned short* pl = &Pld[wid][0];
    const int rc0 = (blk*16) ^ ((l15 & 7) << 4);
    const int rc1 = rc0 ^ 64;

    s16x8 onesf;
    #pragma unroll
    for (int i = 0; i < 8; ++i) onesf[i] = (short)0x3F80;   // bf16 1.0

    f32x4 o[2][4] = {};
    f32x4 sacc[2] = {};
    float m2[2] = {-1e30f, -1e30f};

    s16x8 kr0 = *(const s16x8*)kg0;
    s16x8 kr1 = *(const s16x8*)kg1;
    s16x8 vr0 = *(const s16x8*)vg0;
    s16x8 vr1 = *(const s16x8*)vg1;

    for (int tt = 0; tt < SEQ/64; ++tt) {
        __syncthreads();
        *(s16x8*)((char*)Kld + w0) = kr0;
        *(s16x8*)((char*)Kld + w1) = kr1;
        *(s16x8*)((char*)Vld + w0) = vr0;
        *(s16x8*)((char*)Vld + w1) = vr1;
        __syncthreads();
        if (tt + 1 < SEQ/64) {
            const size_t ko = (size_t)(tt+1)*64;
            kr0 = *(const s16x8*)(kg0 + ko*EMBED);
            kr1 = *(const s16x8*)(kg1 + ko*EMBED);
            vr0 = *(const s16x8*)(vg0 + ko);
            vr1 = *(const s16x8*)(vg1 + ko);
        }

        f32x4 sc[2][4];
        #pragma unroll
        for (int qs = 0; qs < 2; ++qs)
            #pragma unroll
            for (int kt = 0; kt < 4; ++kt)
                sc[qs][kt] = f32x4{0.f,0.f,0.f,0.f};
        __builtin_amdgcn_s_setprio(1);
        #pragma unroll
        for (int kt = 0; kt < 4; ++kt) {
            const char* krow = (const char*)Kld + (kt*16 + l15)*128;
            s16x8 ka0 = *(const s16x8*)(krow + rc0);
            s16x8 ka1 = *(const s16x8*)(krow + rc1);
            #pragma unroll
            for (int qs = 0; qs < 2; ++qs) {
                sc[qs][kt] = MFMA16(ka0, qf[qs][0], sc[qs][kt]);
                sc[qs][kt] = MFMA16(ka1, qf[qs][1], sc[qs][kt]);
            }
        }
        __builtin_amdgcn_s_setprio(0);

        #pragma unroll
        for (int qs = 0; qs < 2; ++qs) {
            const f32x4 s0 = sc[qs][0], s1 = sc[qs][1], s2 = sc[qs][2], s3 = sc[qs][3];
            float p0 = max3f(s0[0], s0[1], s0[2]);
            float p1 = max3f(s0[3], s1[0], s1[1]);
            float p2 = max3f(s1[2], s1[3], s2[0]);
            float p3 = max3f(s2[1], s2[2], s2[3]);
            float p4 = max3f(s3[0], s3[1], s3[2]);
            float pm = fmaxf(max3f(p0, p1, p2), max3f(p3, p4, s3[3]));

            if (!__all((int)(pm <= m2[qs] + 8.f))) {
                float pr = fmaxf(pm, __shfl_xor(pm, 16));
                pr = fmaxf(pr, __shfl_xor(pr, 32));
                const float mn = fmaxf(m2[qs], pr);
                const float al = exp2f(m2[qs] - mn);
                m2[qs] = mn;
                float ar[4];
                #pragma unroll
                for (int r = 0; r < 4; ++r) ar[r] = __shfl(al, blk*4 + r);
                #pragma unroll
                for (int dt = 0; dt < 4; ++dt)
                    #pragma unroll
                    for (int r = 0; r < 4; ++r) o[qs][dt][r] *= ar[r];
                #pragma unroll
                for (int r = 0; r < 4; ++r) sacc[qs][r] *= ar[r];
            }
            const float mn = m2[qs];
            #pragma unroll
            for (int kt = 0; kt < 4; ++kt) {
                const float e0 = exp2f(sc[qs][kt][0] - mn);
                const float e1 = exp2f(sc[qs][kt][1] - mn);
                const float e2 = exp2f(sc[qs][kt][2] - mn);
                const float e3 = exp2f(sc[qs][kt][3] - mn);
                const int off = (qs*16 + l15)*128 + ((kt*32 + blk*8) ^ ((l15 & 7) << 4));
                *(uint2*)((char*)pl + off) = make_uint2(cvtpk(e0,e1), cvtpk(e2,e3));
            }
        }

        s16x8 pa[2][2];
        #pragma unroll
        for (int qs = 0; qs < 2; ++qs) {
            const char* prow = (const char*)pl + (qs*16 + l15)*128;
            pa[qs][0] = *(const s16x8*)(prow + rc0);
            pa[qs][1] = *(const s16x8*)(prow + rc1);
        }
        __builtin_amdgcn_s_setprio(1);
        #pragma unroll
        for (int qs = 0; qs < 2; ++qs) {
            sacc[qs] = MFMA16(pa[qs][0], onesf, sacc[qs]);
            sacc[qs] = MFMA16(pa[qs][1], onesf, sacc[qs]);
        }
        #pragma unroll
        for (int dt = 0; dt < 4; ++dt) {
            const char* vrow = (const char*)Vld + (dt*16 + l15)*128;
            s16x8 vb0 = *(const s16x8*)(vrow + rc0);
            s16x8 vb1 = *(const s16x8*)(vrow + rc1);
            #pragma unroll
            for (int qs = 0; qs < 2; ++qs) {
                o[qs][dt] = MFMA16(pa[qs][0], vb0, o[qs][dt]);
                o[qs][dt] = MFMA16(pa[qs][1], vb1, o[qs][dt]);
            }
        }
        __builtin_amdgcn_s_setprio(0);
    }

    #pragma unroll
    for (int qs = 0; qs < 2; ++qs) {
        float li[4];
        #pragma unroll
        for (int r = 0; r < 4; ++r) li[r] = 1.f / sacc[qs][r];
        unsigned short* cp = ctx + (size_t)(b*SEQ + q0 + qs*16)*EMBED + h*HD;
        #pragma unroll
        for (int dt = 0; dt < 4; ++dt)
            #pragma unroll
            for (int r = 0; r < 4; ++r)
                cp[(size_t)(blk*4 + r)*EMBED + dt*16 + l15] = f2bf(o[qs][dt][r] * li[r]);
    }
}

// ---------------------------------------------------------------------------
extern "C" void kernel_launch(void* const* d_in, const int* in_sizes, int n_in,
                              void* d_out, int out_size, void* d_ws, size_t ws_size,
                              hipStream_t stream)
{
    const float* q  = (const float*)d_in[0];
    const float* k  = (const float*)d_in[1];
    const float* v  = (const float*)d_in[2];
    const float* wq = (const float*)d_in[3];
    const float* bq = (const float*)d_in[4];
    const float* wk = (const float*)d_in[5];
    const float* bk = (const float*)d_in[6];
    const float* wv = (const float*)d_in[7];
    const float* bv = (const float*)d_in[8];
    const float* wo = (const float*)d_in[9];
    const float* bo = (const float*)d_in[10];

    unsigned short* Qp  = (unsigned short*)d_out;          // d_out as scratch
    unsigned short* Kp  = Qp + (size_t)MROWS*EMBED;
    unsigned short* Vt  = (unsigned short*)d_ws;           // [b][h][d][s]
    unsigned short* ctx = Vt + (size_t)MROWS*EMBED;
    float* out = (float*)d_out;

    dim3 g(MROWS/128, EMBED/128), tpb(256);
    gemm_proj<0,1><<<g, tpb, 0, stream>>>(q, wq, bq, Qp);   // Q pre-scaled
    gemm_proj<0,0><<<g, tpb, 0, stream>>>(k, wk, bk, Kp);
    gemm_proj<1,0><<<g, tpb, 0, stream>>>(v, wv, bv, Vt);
    attn_fwd<<<dim3(NB*NH, SEQ/128), tpb, 0, stream>>>(Qp, Kp, Vt, ctx);
    gemm_out<<<dim3(MROWS/128, EMBED/128), tpb, 0, stream>>>(ctx, wo, bo, out);
}